// Round 16
// baseline (273.331 us; speedup 1.0000x reference)
//
#include <hip/hip_runtime.h>
#include <stdint.h>

// Problem constants (fixed by setup_inputs)
#define BB 8
#define DD 32
#define HH 48
#define WW 48
#define HWSZ 2304          // 48*48
#define NROW 18432         // B*HW
#define KQ 8192
#define NCOL 8200          // 8 + 8192

// d_out offsets (floats)
#define OFF_TMP    151142400
#define OFF_LLOG   151160832
#define OFF_LLBL   151271424
#define OFF_SAL    151289856

// mixed grid 1:1: bid even -> gemm g=bid>>1 (4608 blocks, 16 rows x 2048 cols),
// bid odd -> lrow l=bid>>1 (4608 blocks). Total 9216.
#define N_MAIN6  9216

typedef short short8v __attribute__((ext_vector_type(8)));
typedef float float4v __attribute__((ext_vector_type(4)));

// ---------------- threefry2x32 (exact JAX rounds) ----------------
__device__ __forceinline__ uint32_t rotl_d(uint32_t x, int d){
  return __builtin_amdgcn_alignbit(x, x, (uint32_t)(32-d));
}

__device__ __forceinline__ void tf2x32(uint32_t k0, uint32_t k1, uint32_t x0, uint32_t x1,
                                       uint32_t &o0, uint32_t &o1){
  uint32_t ks2 = k0 ^ k1 ^ 0x1BD11BDAu;
  x0 += k0; x1 += k1;
  x0+=x1; x1=rotl_d(x1,13); x1^=x0;
  x0+=x1; x1=rotl_d(x1,15); x1^=x0;
  x0+=x1; x1=rotl_d(x1,26); x1^=x0;
  x0+=x1; x1=rotl_d(x1, 6); x1^=x0;
  x0+=k1; x1+=ks2+1u;
  x0+=x1; x1=rotl_d(x1,17); x1^=x0;
  x0+=x1; x1=rotl_d(x1,29); x1^=x0;
  x0+=x1; x1=rotl_d(x1,16); x1^=x0;
  x0+=x1; x1=rotl_d(x1,24); x1^=x0;
  x0+=ks2; x1+=k0+2u;
  x0+=x1; x1=rotl_d(x1,13); x1^=x0;
  x0+=x1; x1=rotl_d(x1,15); x1^=x0;
  x0+=x1; x1=rotl_d(x1,26); x1^=x0;
  x0+=x1; x1=rotl_d(x1, 6); x1^=x0;
  x0+=k0; x1+=k1+3u;
  x0+=x1; x1=rotl_d(x1,17); x1^=x0;
  x0+=x1; x1=rotl_d(x1,29); x1^=x0;
  x0+=x1; x1=rotl_d(x1,16); x1^=x0;
  x0+=x1; x1=rotl_d(x1,24); x1^=x0;
  x0+=k1; x1+=ks2+4u;
  x0+=x1; x1=rotl_d(x1,13); x1^=x0;
  x0+=x1; x1=rotl_d(x1,15); x1^=x0;
  x0+=x1; x1=rotl_d(x1,26); x1^=x0;
  x0+=x1; x1=rotl_d(x1, 6); x1^=x0;
  x0+=ks2; x1+=k0+5u;
  o0=x0; o1=x1;
}

static inline uint32_t rotl_h(uint32_t x,int d){return (x<<d)|(x>>(32-d));}
static void tf_host(uint32_t k0,uint32_t k1,uint32_t x0,uint32_t x1,uint32_t&o0,uint32_t&o1){
  uint32_t ks2=k0^k1^0x1BD11BDAu;
  x0+=k0;x1+=k1;
  const int RA[4]={13,15,26,6}, RBR[4]={17,29,16,24};
  for(int i=0;i<4;++i){x0+=x1;x1=rotl_h(x1,RA[i]);x1^=x0;}
  x0+=k1; x1+=ks2+1u;
  for(int i=0;i<4;++i){x0+=x1;x1=rotl_h(x1,RBR[i]);x1^=x0;}
  x0+=ks2; x1+=k0+2u;
  for(int i=0;i<4;++i){x0+=x1;x1=rotl_h(x1,RA[i]);x1^=x0;}
  x0+=k0; x1+=k1+3u;
  for(int i=0;i<4;++i){x0+=x1;x1=rotl_h(x1,RBR[i]);x1^=x0;}
  x0+=k1; x1+=ks2+4u;
  for(int i=0;i<4;++i){x0+=x1;x1=rotl_h(x1,RA[i]);x1^=x0;}
  x0+=ks2; x1+=k0+5u;
  o0=x0;o1=x1;
}

__device__ __forceinline__ ushort f2bf(float x){
  uint32_t u = __float_as_uint(x);
  uint32_t r = (u + 0x7FFFu + ((u>>16)&1u)) >> 16;
  return (ushort)r;
}

// ---------------- fused prologue: qnorm | wk+protos | qn | sal by block role ----------------
__global__ __launch_bounds__(256) void k_pre(const float* __restrict__ q_feat,
                                             const float* __restrict__ k_feat,
                                             const float* __restrict__ q_bg,
                                             const float* __restrict__ sal_q,
                                             const float* __restrict__ sal_k,
                                             const float* __restrict__ queue,
                                             float* __restrict__ q_flat,
                                             ushort* __restrict__ qbf,
                                             ushort* __restrict__ qnT,
                                             float* __restrict__ praw,
                                             float* __restrict__ tmp_out,
                                             float* __restrict__ lbl_out,
                                             float* __restrict__ acc){
  __shared__ float pacc[32];
  int bid = blockIdx.x;
  if (bid < 72){
    // ---- qnorm: normalize q_feat over D, coalesced; emit fp32 + bf16 rows ----
    int b = bid / 9;
    int hw = (bid % 9)*256 + threadIdx.x;
    const float* src = q_feat + (size_t)b*DD*HWSZ + hw;
    float v[32]; float ss = 0.f;
#pragma unroll
    for (int d=0; d<32; ++d){ v[d] = src[(size_t)d*HWSZ]; ss += v[d]*v[d]; }
    float inv = 1.f / fmaxf(sqrtf(ss), 1e-12f);
    size_t row = (size_t)b*HWSZ + hw;
    float4* o4 = (float4*)(q_flat + row*DD);
#pragma unroll
    for (int i=0;i<8;++i)
      o4[i] = make_float4(v[4*i]*inv, v[4*i+1]*inv, v[4*i+2]*inv, v[4*i+3]*inv);
    ushort us[32];
#pragma unroll
    for (int d=0; d<32; ++d) us[d] = f2bf(v[d]*inv);
    short8v* ob = (short8v*)(qbf + row*DD);
#pragma unroll
    for (int i=0;i<4;++i) ob[i] = *(short8v*)&us[8*i];
  } else if (bid < 144){
    // ---- wk + protos partial: w = sal_k/||k||; praw[b,d] += sum v[d]*w ----
    int rb = bid - 72;
    int b = rb / 9;
    int hw = (rb % 9)*256 + threadIdx.x;
    const float* src = k_feat + (size_t)b*DD*HWSZ + hw;
    float v[32]; float ss = 0.f;
#pragma unroll
    for (int d=0; d<32; ++d){ v[d] = src[(size_t)d*HWSZ]; ss += v[d]*v[d]; }
    float w_t = sal_k[(size_t)b*HWSZ + hw] * (1.f / fmaxf(sqrtf(ss), 1e-12f));
    if (threadIdx.x < 32) pacc[threadIdx.x] = 0.f;
    __syncthreads();
    int lane = threadIdx.x & 63;
#pragma unroll
    for (int d=0; d<32; ++d){
      float s = v[d]*w_t;
      s+=__shfl_xor(s,32,64); s+=__shfl_xor(s,16,64); s+=__shfl_xor(s,8,64);
      s+=__shfl_xor(s,4,64);  s+=__shfl_xor(s,2,64);  s+=__shfl_xor(s,1,64);
      if (lane==0) atomicAdd(&pacc[d], s);
    }
    __syncthreads();
    if (threadIdx.x < 32) atomicAdd(&praw[b*32 + threadIdx.x], pacc[threadIdx.x]);
  } else if (bid < 176){
    // ---- qn: queue column-normalize -> qnT bf16 [8192][32] ----
    int j = (bid-144)*256 + threadIdx.x;
    float v[32]; float ss = 0.f;
#pragma unroll
    for (int d=0; d<DD; ++d){ v[d] = queue[(size_t)d*KQ + j]; ss += v[d]*v[d]; }
    float inv = 1.f / fmaxf(sqrtf(ss), 1e-12f);
    ushort us[32];
#pragma unroll
    for (int d=0; d<DD; ++d) us[d] = f2bf(v[d]*inv);
    short8v* ob = (short8v*)(qnT + (size_t)j*DD);
#pragma unroll
    for (int i=0;i<4;++i) ob[i] = *(short8v*)&us[8*i];
  } else {
    // ---- sal: tmp, labels, balanced-BCE partials ----
    int i = (bid-176)*256 + threadIdx.x;
    float s = sal_q[i];
    int b = i / HWSZ;
    float tmpv = (s + 2.f*(float)b) * s;
    __builtin_nontemporal_store(floorf(tmpv * 0.5f), &tmp_out[i]);
    __builtin_nontemporal_store(0.f, &lbl_out[i]);
    float x = q_bg[i];
    float c = log1pf(expf(-fabsf(x)));
    float sp_neg = fmaxf(-x,0.f) + c;
    float sp_pos = fmaxf( x,0.f) + c;
    float loss = sp_neg*s + sp_pos*(1.f - s);
    float a0 = s, a1 = s*loss, a2 = (1.f-s)*loss;
    a0+=__shfl_xor(a0,32,64); a1+=__shfl_xor(a1,32,64); a2+=__shfl_xor(a2,32,64);
    a0+=__shfl_xor(a0,16,64); a1+=__shfl_xor(a1,16,64); a2+=__shfl_xor(a2,16,64);
    a0+=__shfl_xor(a0, 8,64); a1+=__shfl_xor(a1, 8,64); a2+=__shfl_xor(a2, 8,64);
    a0+=__shfl_xor(a0, 4,64); a1+=__shfl_xor(a1, 4,64); a2+=__shfl_xor(a2, 4,64);
    a0+=__shfl_xor(a0, 2,64); a1+=__shfl_xor(a2, 2,64)*0.f + __shfl_xor(a1, 2,64); a2+=__shfl_xor(a2, 2,64);
    a0+=__shfl_xor(a0, 1,64); a1+=__shfl_xor(a1, 1,64); a2+=__shfl_xor(a2, 1,64);
    if ((threadIdx.x&63)==0){ atomicAdd(&acc[0],a0); atomicAdd(&acc[1],a1); atomicAdd(&acc[2],a2); }
  }
}

// pnorm + BCE finalize (one block)
__global__ __launch_bounds__(256) void k_pnormfin(const float* __restrict__ praw, float* __restrict__ pn,
                                                  const float* __restrict__ acc, float* __restrict__ out_sal){
  int t = threadIdx.x;
  float v = praw[t];
  float ss = v*v;
  ss += __shfl_xor(ss,16,64); ss+=__shfl_xor(ss,8,64); ss+=__shfl_xor(ss,4,64);
  ss+=__shfl_xor(ss,2,64); ss+=__shfl_xor(ss,1,64);
  pn[t] = v / fmaxf(sqrtf(ss), 1e-12f);
  if (t == 0){
    float numel = (float)NROW;
    float npos = acc[0];
    float nneg = numel - npos;
    out_sal[0] = (nneg/numel*acc[1] + npos/numel*acc[2]) / numel;
  }
}

// ---------------- mega-kernel: GEMM (16r x 2048c) | lrow, 1:1 by block parity ----------------
__global__ __launch_bounds__(256, 8) void k_main(const float* __restrict__ q_flat,
                                              const ushort* __restrict__ qbf,
                                              const ushort* __restrict__ qnT,
                                              const float* __restrict__ pn,
                                              float* __restrict__ out,
                                              float* __restrict__ llog,
                                              uint32_t kd0, uint32_t kd1,
                                              uint32_t kn0, uint32_t kn1){
  __shared__ float lds[16*260];
  int bid = blockIdx.x;
  int wave = threadIdx.x>>6, lane = threadIdx.x&63;

  if ((bid & 1) == 0){
    // ================= GEMM role: 16 rows x 2048 cols =================
    int g = bid>>1;                // 0..4607
    int rowbase = (g>>2)*16;
    int colq = (g&3)*2048;
    int r16 = lane&15, hi = lane>>4, koff = hi*8;

    const short8v a = *(const short8v*)(qbf + ((size_t)(rowbase + r16))*DD + koff);

    // head: cols 0..7 = 2 * q_flat @ pn^T (fp32), threads 0..31, quarter-0 blocks only
    if ((g&3)==0 && threadIdx.x < 32){
      int row = threadIdx.x >> 1, c0 = (threadIdx.x & 1)*4;
      const float* qr = q_flat + (size_t)(rowbase+row)*DD;
      float s0=0.f,s1=0.f,s2=0.f,s3=0.f;
#pragma unroll
      for (int d=0; d<32; ++d){
        float qd = qr[d];
        s0 += qd*pn[(c0+0)*32+d];
        s1 += qd*pn[(c0+1)*32+d];
        s2 += qd*pn[(c0+2)*32+d];
        s3 += qd*pn[(c0+3)*32+d];
      }
      float4v hv = {2.f*s0, 2.f*s1, 2.f*s2, 2.f*s3};
      __builtin_nontemporal_store(hv,
          (float4v*)(out + (size_t)(rowbase+row)*NCOL + c0));
    }

    // 8 chunks of 256 cols; each chunk: MFMA -> LDS -> nt streaming stores
    for (int c=0; c<8; ++c){
      int chunkbase = colq + c*256;
#pragma unroll
      for (int t=0; t<4; ++t){
        int j0 = chunkbase + wave*64 + t*16;
        const short8v bfr = *(const short8v*)(qnT + ((size_t)(j0 + r16))*DD + koff);
        float4v acc = {0.f,0.f,0.f,0.f};
        acc = __builtin_amdgcn_mfma_f32_16x16x32_bf16(a, bfr, acc, 0, 0, 0);
        int ccol = wave*64 + t*16 + r16;
#pragma unroll
        for (int i=0;i<4;++i) lds[(hi*4+i)*260 + ccol] = 2.f*acc[i];
      }
      __syncthreads();
#pragma unroll
      for (int k=0;k<4;++k){
        int f = threadIdx.x + k*256;
        int row = f>>6, col4 = f&63;
        float4v v = *(const float4v*)&lds[row*260 + col4*4];
        __builtin_nontemporal_store(v,
            (float4v*)(out + (size_t)(rowbase+row)*NCOL + 8 + chunkbase + col4*4));
      }
      __syncthreads();
    }
  } else {
    // ================= lrow role: positive + top-5 negatives for 4 rows =================
    int l = bid>>1;               // 0..4607
    int row = l*4 + wave;         // b*HW + h
    int b = row/HWSZ, h = row%HWSZ;
    int r = h/WW, c0 = h%WW;

    // positive: direction argmax
    uint32_t m = 0;
    if (lane < 4){
      uint32_t i = (uint32_t)row*4u + (uint32_t)lane;
      uint32_t o0,o1;
      tf2x32(kd0,kd1,0u,i,o0,o1);
      m = (o0 ^ o1) >> 9;
    }
    uint32_t mm[4];
    mm[0]=__shfl(m,0,64); mm[1]=__shfl(m,1,64); mm[2]=__shfl(m,2,64); mm[3]=__shfl(m,3,64);
    const int sr[4]={1,-1,0,0}, sc[4]={0,0,1,-1};
    int best=-1; uint32_t bv=0;
#pragma unroll
    for (int j=0;j<4;++j){
      int nr=r+sr[j], nc=c0+sc[j];
      bool ok = (nr>=0)&&(nr<HH)&&(nc>=0)&&(nc<WW);
      if (ok && (best<0 || mm[j]>bv)){ best=j; bv=mm[j]; }
    }
    int pos = (r+sr[best])*WW + (c0+sc[best]);
    int prow = b*HWSZ + pos;

    float qv = 0.f, pv = 0.f;
    if (lane<32){ qv=q_flat[(size_t)row*DD+lane]; pv=q_flat[(size_t)prow*DD+lane]; }
    float d = qv*pv;
    d+=__shfl_xor(d,16,64); d+=__shfl_xor(d,8,64); d+=__shfl_xor(d,4,64);
    d+=__shfl_xor(d,2,64); d+=__shfl_xor(d,1,64);
    if (lane==0) llog[(size_t)row*6] = 2.f*d;

    // negatives: branchless per-lane top-5 (32-bit keys) over 36 elements
    uint32_t base = (uint32_t)row * (uint32_t)HWSZ + (uint32_t)lane;
    uint32_t t0=0,t1=0,t2=0,t3=0,t4=0;
#pragma unroll 4
    for (int it=0; it<36; ++it){
      uint32_t o0,o1;
      tf2x32(kn0,kn1,0u, base + (uint32_t)(it<<6), o0,o1);
      int c = lane + (it<<6);
      uint32_t key = (((o0^o1)>>3)&0xFFFFFFC0u) | (uint32_t)(35-it);
      key = (c != h) ? key : 0u;
      uint32_t mx, mn;
      mx = t0>key?t0:key; mn = t0>key?key:t0; t0=mx; key=mn;
      mx = t1>key?t1:key; mn = t1>key?key:t1; t1=mx; key=mn;
      mx = t2>key?t2:key; mn = t2>key?key:t2; t2=mx; key=mn;
      mx = t3>key?t3:key; mn = t3>key?key:t3; t3=mx; key=mn;
      t4 = t4>key?t4:key;
    }
    int idx[5];
#pragma unroll
    for (int k=0;k<5;++k){
      uint32_t mk = t0>>6;
      int it = 35 - (int)(t0 & 63u);
      int c  = lane + (it<<6);
      unsigned long long bk = ((unsigned long long)mk<<18)
                            | ((unsigned long long)(2303-c)<<6)
                            | (unsigned long long)lane;
      #pragma unroll
      for (int o=1;o<64;o<<=1){
        unsigned long long other = __shfl_xor(bk,o,64);
        if (other > bk) bk = other;
      }
      int wl = (int)(bk & 63ull);
      idx[k] = 2303 - (int)((bk >> 6) & 0xFFFull);
      if (lane == wl){ t0=t1; t1=t2; t2=t3; t3=t4; t4=0; }
    }
#pragma unroll
    for (int k=0;k<5;++k){
      float nv = 0.f;
      if (lane < 32) nv = q_flat[(size_t)(b*HWSZ + idx[k])*DD + lane];
      float dd = qv*nv;
      dd+=__shfl_xor(dd,16,64); dd+=__shfl_xor(dd,8,64); dd+=__shfl_xor(dd,4,64);
      dd+=__shfl_xor(dd,2,64); dd+=__shfl_xor(dd,1,64);
      if (lane==0) llog[(size_t)row*6 + 1 + k] = 2.f*dd;
    }
  }
}

extern "C" void kernel_launch(void* const* d_in, const int* in_sizes, int n_in,
                              void* d_out, int out_size, void* d_ws, size_t ws_size,
                              hipStream_t stream) {
  const float* q_feat = (const float*)d_in[0];
  const float* k_feat = (const float*)d_in[1];
  const float* q_bg   = (const float*)d_in[2];
  const float* sal_q  = (const float*)d_in[3];
  const float* sal_k  = (const float*)d_in[4];
  const float* queue  = (const float*)d_in[5];
  (void)in_sizes; (void)n_in; (void)out_size; (void)ws_size;

  float* out    = (float*)d_out;
  float* logits = out;
  float* tmp    = out + OFF_TMP;
  float* llog   = out + OFF_LLOG;
  float* llbl   = out + OFF_LLBL;
  float* sal    = out + OFF_SAL;

  float* ws     = (float*)d_ws;
  float*  q_flat = ws;                                // 589824 f
  ushort* qbf    = (ushort*)(ws + 589824);            // 589824 us = 294912 f
  ushort* qnT    = (ushort*)(ws + 884736);            // 262144 us = 131072 f
  float*  praw   = ws + 1015808;                      // 256
  float*  acc    = ws + 1016064;                      // 3   (adjacent to praw for one memset)
  float*  pn     = ws + 1016128;                      // 256

  // JAX partitionable threefry: split(key(42)): keys[i] = tf((0,42), 0, i)
  uint32_t kd0,kd1,kn0,kn1;
  tf_host(0u,42u,0u,0u,kd0,kd1);   // k_dir
  tf_host(0u,42u,0u,1u,kn0,kn1);   // k_neg

  (void)hipMemsetAsync(praw, 0, 259*sizeof(float), stream);   // praw + acc

  k_pre     <<<248, 256, 0, stream>>>(q_feat, k_feat, q_bg, sal_q, sal_k, queue,
                                      q_flat, qbf, qnT, praw, tmp, llbl, acc);
  k_pnormfin<<<1,   256, 0, stream>>>(praw, pn, acc, sal);
  k_main    <<<N_MAIN6, 256, 0, stream>>>(q_flat, qbf, qnT, pn, logits, llog,
                                          kd0, kd1, kn0, kn1);
}

// Round 17
// 177.377 us; speedup vs baseline: 1.5410x; 1.5410x over previous
//
#include <hip/hip_runtime.h>
#include <stdint.h>

// Problem constants (fixed by setup_inputs)
#define BB 8
#define DD 32
#define HH 48
#define WW 48
#define HWSZ 2304          // 48*48
#define NROW 18432         // B*HW
#define KQ 8192
#define NCOL 8200          // 8 + 8192

// d_out offsets (floats)
#define OFF_TMP    151142400
#define OFF_LLOG   151160832
#define OFF_LLBL   151271424
#define OFF_SAL    151289856

// mixed grid: bid%3==0 -> gemm (2304 blocks, 16 rows x 4096 cols),
// else lrow (4608 blocks). Total 6912.  (R15 champion mapping)
#define N_MAIN4  6912

typedef short short8v __attribute__((ext_vector_type(8)));
typedef float float4v __attribute__((ext_vector_type(4)));

// raw barrier: NO vmcnt drain (keeps nt stores in flight across chunks).
// lgkmcnt(0) gives LDS write-visibility / read-completion ordering.
__device__ __forceinline__ void lds_barrier(){
  asm volatile("s_waitcnt lgkmcnt(0)" ::: "memory");
  __builtin_amdgcn_s_barrier();
  asm volatile("" ::: "memory");
}

// ---------------- threefry2x32 (exact JAX rounds) ----------------
__device__ __forceinline__ uint32_t rotl_d(uint32_t x, int d){
  return __builtin_amdgcn_alignbit(x, x, (uint32_t)(32-d));
}

__device__ __forceinline__ void tf2x32(uint32_t k0, uint32_t k1, uint32_t x0, uint32_t x1,
                                       uint32_t &o0, uint32_t &o1){
  uint32_t ks2 = k0 ^ k1 ^ 0x1BD11BDAu;
  x0 += k0; x1 += k1;
  x0+=x1; x1=rotl_d(x1,13); x1^=x0;
  x0+=x1; x1=rotl_d(x1,15); x1^=x0;
  x0+=x1; x1=rotl_d(x1,26); x1^=x0;
  x0+=x1; x1=rotl_d(x1, 6); x1^=x0;
  x0+=k1; x1+=ks2+1u;
  x0+=x1; x1=rotl_d(x1,17); x1^=x0;
  x0+=x1; x1=rotl_d(x1,29); x1^=x0;
  x0+=x1; x1=rotl_d(x1,16); x1^=x0;
  x0+=x1; x1=rotl_d(x1,24); x1^=x0;
  x0+=ks2; x1+=k0+2u;
  x0+=x1; x1=rotl_d(x1,13); x1^=x0;
  x0+=x1; x1=rotl_d(x1,15); x1^=x0;
  x0+=x1; x1=rotl_d(x1,26); x1^=x0;
  x0+=x1; x1=rotl_d(x1, 6); x1^=x0;
  x0+=k0; x1+=k1+3u;
  x0+=x1; x1=rotl_d(x1,17); x1^=x0;
  x0+=x1; x1=rotl_d(x1,29); x1^=x0;
  x0+=x1; x1=rotl_d(x1,16); x1^=x0;
  x0+=x1; x1=rotl_d(x1,24); x1^=x0;
  x0+=k1; x1+=ks2+4u;
  x0+=x1; x1=rotl_d(x1,13); x1^=x0;
  x0+=x1; x1=rotl_d(x1,15); x1^=x0;
  x0+=x1; x1=rotl_d(x1,26); x1^=x0;
  x0+=x1; x1=rotl_d(x1, 6); x1^=x0;
  x0+=ks2; x1+=k0+5u;
  o0=x0; o1=x1;
}

static inline uint32_t rotl_h(uint32_t x,int d){return (x<<d)|(x>>(32-d));}
static void tf_host(uint32_t k0,uint32_t k1,uint32_t x0,uint32_t x1,uint32_t&o0,uint32_t&o1){
  uint32_t ks2=k0^k1^0x1BD11BDAu;
  x0+=k0;x1+=k1;
  const int RA[4]={13,15,26,6}, RBR[4]={17,29,16,24};
  for(int i=0;i<4;++i){x0+=x1;x1=rotl_h(x1,RA[i]);x1^=x0;}
  x0+=k1; x1+=ks2+1u;
  for(int i=0;i<4;++i){x0+=x1;x1=rotl_h(x1,RBR[i]);x1^=x0;}
  x0+=ks2; x1+=k0+2u;
  for(int i=0;i<4;++i){x0+=x1;x1=rotl_h(x1,RA[i]);x1^=x0;}
  x0+=k0; x1+=k1+3u;
  for(int i=0;i<4;++i){x0+=x1;x1=rotl_h(x1,RBR[i]);x1^=x0;}
  x0+=k1; x1+=ks2+4u;
  for(int i=0;i<4;++i){x0+=x1;x1=rotl_h(x1,RA[i]);x1^=x0;}
  x0+=ks2; x1+=k0+5u;
  o0=x0;o1=x1;
}

__device__ __forceinline__ ushort f2bf(float x){
  uint32_t u = __float_as_uint(x);
  uint32_t r = (u + 0x7FFFu + ((u>>16)&1u)) >> 16;
  return (ushort)r;
}

// ---------------- fused prologue: qnorm | wk+protos | qn | sal by block role ----------------
__global__ __launch_bounds__(256) void k_pre(const float* __restrict__ q_feat,
                                             const float* __restrict__ k_feat,
                                             const float* __restrict__ q_bg,
                                             const float* __restrict__ sal_q,
                                             const float* __restrict__ sal_k,
                                             const float* __restrict__ queue,
                                             float* __restrict__ q_flat,
                                             ushort* __restrict__ qbf,
                                             ushort* __restrict__ qnT,
                                             float* __restrict__ praw,
                                             float* __restrict__ tmp_out,
                                             float* __restrict__ lbl_out,
                                             float* __restrict__ acc){
  __shared__ float pacc[32];
  int bid = blockIdx.x;
  if (bid < 72){
    // ---- qnorm: normalize q_feat over D, coalesced; emit fp32 + bf16 rows ----
    int b = bid / 9;
    int hw = (bid % 9)*256 + threadIdx.x;
    const float* src = q_feat + (size_t)b*DD*HWSZ + hw;
    float v[32]; float ss = 0.f;
#pragma unroll
    for (int d=0; d<32; ++d){ v[d] = src[(size_t)d*HWSZ]; ss += v[d]*v[d]; }
    float inv = 1.f / fmaxf(sqrtf(ss), 1e-12f);
    size_t row = (size_t)b*HWSZ + hw;
    float4* o4 = (float4*)(q_flat + row*DD);
#pragma unroll
    for (int i=0;i<8;++i)
      o4[i] = make_float4(v[4*i]*inv, v[4*i+1]*inv, v[4*i+2]*inv, v[4*i+3]*inv);
    ushort us[32];
#pragma unroll
    for (int d=0; d<32; ++d) us[d] = f2bf(v[d]*inv);
    short8v* ob = (short8v*)(qbf + row*DD);
#pragma unroll
    for (int i=0;i<4;++i) ob[i] = *(short8v*)&us[8*i];
  } else if (bid < 144){
    // ---- wk + protos partial: w = sal_k/||k||; praw[b,d] += sum v[d]*w ----
    int rb = bid - 72;
    int b = rb / 9;
    int hw = (rb % 9)*256 + threadIdx.x;
    const float* src = k_feat + (size_t)b*DD*HWSZ + hw;
    float v[32]; float ss = 0.f;
#pragma unroll
    for (int d=0; d<32; ++d){ v[d] = src[(size_t)d*HWSZ]; ss += v[d]*v[d]; }
    float w_t = sal_k[(size_t)b*HWSZ + hw] * (1.f / fmaxf(sqrtf(ss), 1e-12f));
    if (threadIdx.x < 32) pacc[threadIdx.x] = 0.f;
    __syncthreads();
    int lane = threadIdx.x & 63;
#pragma unroll
    for (int d=0; d<32; ++d){
      float s = v[d]*w_t;
      s+=__shfl_xor(s,32,64); s+=__shfl_xor(s,16,64); s+=__shfl_xor(s,8,64);
      s+=__shfl_xor(s,4,64);  s+=__shfl_xor(s,2,64);  s+=__shfl_xor(s,1,64);
      if (lane==0) atomicAdd(&pacc[d], s);
    }
    __syncthreads();
    if (threadIdx.x < 32) atomicAdd(&praw[b*32 + threadIdx.x], pacc[threadIdx.x]);
  } else if (bid < 176){
    // ---- qn: queue column-normalize -> qnT bf16 [8192][32] ----
    int j = (bid-144)*256 + threadIdx.x;
    float v[32]; float ss = 0.f;
#pragma unroll
    for (int d=0; d<DD; ++d){ v[d] = queue[(size_t)d*KQ + j]; ss += v[d]*v[d]; }
    float inv = 1.f / fmaxf(sqrtf(ss), 1e-12f);
    ushort us[32];
#pragma unroll
    for (int d=0; d<DD; ++d) us[d] = f2bf(v[d]*inv);
    short8v* ob = (short8v*)(qnT + (size_t)j*DD);
#pragma unroll
    for (int i=0;i<4;++i) ob[i] = *(short8v*)&us[8*i];
  } else {
    // ---- sal: tmp, labels, balanced-BCE partials ----
    int i = (bid-176)*256 + threadIdx.x;
    float s = sal_q[i];
    int b = i / HWSZ;
    float tmpv = (s + 2.f*(float)b) * s;
    __builtin_nontemporal_store(floorf(tmpv * 0.5f), &tmp_out[i]);
    __builtin_nontemporal_store(0.f, &lbl_out[i]);
    float x = q_bg[i];
    float c = log1pf(expf(-fabsf(x)));
    float sp_neg = fmaxf(-x,0.f) + c;
    float sp_pos = fmaxf( x,0.f) + c;
    float loss = sp_neg*s + sp_pos*(1.f - s);
    float a0 = s, a1 = s*loss, a2 = (1.f-s)*loss;
    a0+=__shfl_xor(a0,32,64); a1+=__shfl_xor(a1,32,64); a2+=__shfl_xor(a2,32,64);
    a0+=__shfl_xor(a0,16,64); a1+=__shfl_xor(a1,16,64); a2+=__shfl_xor(a2,16,64);
    a0+=__shfl_xor(a0, 8,64); a1+=__shfl_xor(a1, 8,64); a2+=__shfl_xor(a2, 8,64);
    a0+=__shfl_xor(a0, 4,64); a1+=__shfl_xor(a1, 4,64); a2+=__shfl_xor(a2, 4,64);
    a0+=__shfl_xor(a0, 2,64); a1+=__shfl_xor(a1, 2,64); a2+=__shfl_xor(a2, 2,64);
    a0+=__shfl_xor(a0, 1,64); a1+=__shfl_xor(a1, 1,64); a2+=__shfl_xor(a2, 1,64);
    if ((threadIdx.x&63)==0){ atomicAdd(&acc[0],a0); atomicAdd(&acc[1],a1); atomicAdd(&acc[2],a2); }
  }
}

// pnorm + BCE finalize (one block)
__global__ __launch_bounds__(256) void k_pnormfin(const float* __restrict__ praw, float* __restrict__ pn,
                                                  const float* __restrict__ acc, float* __restrict__ out_sal){
  int t = threadIdx.x;
  float v = praw[t];
  float ss = v*v;
  ss += __shfl_xor(ss,16,64); ss+=__shfl_xor(ss,8,64); ss+=__shfl_xor(ss,4,64);
  ss+=__shfl_xor(ss,2,64); ss+=__shfl_xor(ss,1,64);
  pn[t] = v / fmaxf(sqrtf(ss), 1e-12f);
  if (t == 0){
    float numel = (float)NROW;
    float npos = acc[0];
    float nneg = numel - npos;
    out_sal[0] = (nneg/numel*acc[1] + npos/numel*acc[2]) / numel;
  }
}

// ---------------- mega-kernel: GEMM (16r x 4096c) | lrow by block role ----------------
// bid%3==0: gemm g=bid/3 (rows (g>>1)*16, col-half g&1); else lrow.
// Raw lds_barrier (no vmcnt drain) keeps nt stores pipelined across chunks.
__global__ __launch_bounds__(256, 8) void k_main(const float* __restrict__ q_flat,
                                              const ushort* __restrict__ qbf,
                                              const ushort* __restrict__ qnT,
                                              const float* __restrict__ pn,
                                              float* __restrict__ out,
                                              float* __restrict__ llog,
                                              uint32_t kd0, uint32_t kd1,
                                              uint32_t kn0, uint32_t kn1){
  __shared__ float lds[16*260];
  int bid = blockIdx.x;
  int wave = threadIdx.x>>6, lane = threadIdx.x&63;

  if ((bid % 3) == 0){
    // ================= GEMM role: 16 rows x 4096 cols =================
    int g = bid/3;                 // 0..2303
    int rowbase = (g>>1)*16;
    int colhalf = (g&1)*4096;
    int r16 = lane&15, hi = lane>>4, koff = hi*8;

    const short8v a = *(const short8v*)(qbf + ((size_t)(rowbase + r16))*DD + koff);

    // head: cols 0..7 = 2 * q_flat @ pn^T (fp32), threads 0..31, half-0 blocks only
    if ((g&1)==0 && threadIdx.x < 32){
      int row = threadIdx.x >> 1, c0 = (threadIdx.x & 1)*4;
      const float* qr = q_flat + (size_t)(rowbase+row)*DD;
      float s0=0.f,s1=0.f,s2=0.f,s3=0.f;
#pragma unroll
      for (int d=0; d<32; ++d){
        float qd = qr[d];
        s0 += qd*pn[(c0+0)*32+d];
        s1 += qd*pn[(c0+1)*32+d];
        s2 += qd*pn[(c0+2)*32+d];
        s3 += qd*pn[(c0+3)*32+d];
      }
      float4v hv = {2.f*s0, 2.f*s1, 2.f*s2, 2.f*s3};
      __builtin_nontemporal_store(hv,
          (float4v*)(out + (size_t)(rowbase+row)*NCOL + c0));
    }

    // 16 chunks of 256 cols; each chunk: MFMA -> LDS -> nt streaming stores.
    // lds_barrier = lgkmcnt(0)+s_barrier only: stores stay in flight.
    for (int c=0; c<16; ++c){
      int chunkbase = colhalf + c*256;
#pragma unroll
      for (int t=0; t<4; ++t){
        int j0 = chunkbase + wave*64 + t*16;
        const short8v bfr = *(const short8v*)(qnT + ((size_t)(j0 + r16))*DD + koff);
        float4v acc = {0.f,0.f,0.f,0.f};
        acc = __builtin_amdgcn_mfma_f32_16x16x32_bf16(a, bfr, acc, 0, 0, 0);
        int ccol = wave*64 + t*16 + r16;
#pragma unroll
        for (int i=0;i<4;++i) lds[(hi*4+i)*260 + ccol] = 2.f*acc[i];
      }
      lds_barrier();
#pragma unroll
      for (int k=0;k<4;++k){
        int f = threadIdx.x + k*256;
        int row = f>>6, col4 = f&63;
        float4v v = *(const float4v*)&lds[row*260 + col4*4];
        __builtin_nontemporal_store(v,
            (float4v*)(out + (size_t)(rowbase+row)*NCOL + 8 + chunkbase + col4*4));
      }
      lds_barrier();
    }
  } else {
    // ================= lrow role: positive + top-5 negatives for 4 rows =================
    int l = bid - bid/3 - 1;      // 0..4607
    int row = l*4 + wave;         // b*HW + h
    int b = row/HWSZ, h = row%HWSZ;
    int r = h/WW, c0 = h%WW;

    // positive: direction argmax
    uint32_t m = 0;
    if (lane < 4){
      uint32_t i = (uint32_t)row*4u + (uint32_t)lane;
      uint32_t o0,o1;
      tf2x32(kd0,kd1,0u,i,o0,o1);
      m = (o0 ^ o1) >> 9;
    }
    uint32_t mm[4];
    mm[0]=__shfl(m,0,64); mm[1]=__shfl(m,1,64); mm[2]=__shfl(m,2,64); mm[3]=__shfl(m,3,64);
    const int sr[4]={1,-1,0,0}, sc[4]={0,0,1,-1};
    int best=-1; uint32_t bv=0;
#pragma unroll
    for (int j=0;j<4;++j){
      int nr=r+sr[j], nc=c0+sc[j];
      bool ok = (nr>=0)&&(nr<HH)&&(nc>=0)&&(nc<WW);
      if (ok && (best<0 || mm[j]>bv)){ best=j; bv=mm[j]; }
    }
    int pos = (r+sr[best])*WW + (c0+sc[best]);
    int prow = b*HWSZ + pos;

    float qv = 0.f, pv = 0.f;
    if (lane<32){ qv=q_flat[(size_t)row*DD+lane]; pv=q_flat[(size_t)prow*DD+lane]; }
    float d = qv*pv;
    d+=__shfl_xor(d,16,64); d+=__shfl_xor(d,8,64); d+=__shfl_xor(d,4,64);
    d+=__shfl_xor(d,2,64); d+=__shfl_xor(d,1,64);
    if (lane==0) llog[(size_t)row*6] = 2.f*d;

    // negatives: branchless per-lane top-5 (32-bit keys) over 36 elements
    uint32_t base = (uint32_t)row * (uint32_t)HWSZ + (uint32_t)lane;
    uint32_t t0=0,t1=0,t2=0,t3=0,t4=0;
#pragma unroll 4
    for (int it=0; it<36; ++it){
      uint32_t o0,o1;
      tf2x32(kn0,kn1,0u, base + (uint32_t)(it<<6), o0,o1);
      int c = lane + (it<<6);
      uint32_t key = (((o0^o1)>>3)&0xFFFFFFC0u) | (uint32_t)(35-it);
      key = (c != h) ? key : 0u;
      uint32_t mx, mn;
      mx = t0>key?t0:key; mn = t0>key?key:t0; t0=mx; key=mn;
      mx = t1>key?t1:key; mn = t1>key?key:t1; t1=mx; key=mn;
      mx = t2>key?t2:key; mn = t2>key?key:t2; t2=mx; key=mn;
      mx = t3>key?t3:key; mn = t3>key?key:t3; t3=mx; key=mn;
      t4 = t4>key?t4:key;
    }
    int idx[5];
#pragma unroll
    for (int k=0;k<5;++k){
      uint32_t mk = t0>>6;
      int it = 35 - (int)(t0 & 63u);
      int c  = lane + (it<<6);
      unsigned long long bk = ((unsigned long long)mk<<18)
                            | ((unsigned long long)(2303-c)<<6)
                            | (unsigned long long)lane;
      #pragma unroll
      for (int o=1;o<64;o<<=1){
        unsigned long long other = __shfl_xor(bk,o,64);
        if (other > bk) bk = other;
      }
      int wl = (int)(bk & 63ull);
      idx[k] = 2303 - (int)((bk >> 6) & 0xFFFull);
      if (lane == wl){ t0=t1; t1=t2; t2=t3; t3=t4; t4=0; }
    }
#pragma unroll
    for (int k=0;k<5;++k){
      float nv = 0.f;
      if (lane < 32) nv = q_flat[(size_t)(b*HWSZ + idx[k])*DD + lane];
      float dd = qv*nv;
      dd+=__shfl_xor(dd,16,64); dd+=__shfl_xor(dd,8,64); dd+=__shfl_xor(dd,4,64);
      dd+=__shfl_xor(dd,2,64); dd+=__shfl_xor(dd,1,64);
      if (lane==0) llog[(size_t)row*6 + 1 + k] = 2.f*dd;
    }
  }
}

extern "C" void kernel_launch(void* const* d_in, const int* in_sizes, int n_in,
                              void* d_out, int out_size, void* d_ws, size_t ws_size,
                              hipStream_t stream) {
  const float* q_feat = (const float*)d_in[0];
  const float* k_feat = (const float*)d_in[1];
  const float* q_bg   = (const float*)d_in[2];
  const float* sal_q  = (const float*)d_in[3];
  const float* sal_k  = (const float*)d_in[4];
  const float* queue  = (const float*)d_in[5];
  (void)in_sizes; (void)n_in; (void)out_size; (void)ws_size;

  float* out    = (float*)d_out;
  float* logits = out;
  float* tmp    = out + OFF_TMP;
  float* llog   = out + OFF_LLOG;
  float* llbl   = out + OFF_LLBL;
  float* sal    = out + OFF_SAL;

  float* ws     = (float*)d_ws;
  float*  q_flat = ws;                                // 589824 f
  ushort* qbf    = (ushort*)(ws + 589824);            // 589824 us = 294912 f
  ushort* qnT    = (ushort*)(ws + 884736);            // 262144 us = 131072 f
  float*  praw   = ws + 1015808;                      // 256
  float*  acc    = ws + 1016064;                      // 3   (adjacent to praw for one memset)
  float*  pn     = ws + 1016128;                      // 256

  // JAX partitionable threefry: split(key(42)): keys[i] = tf((0,42), 0, i)
  uint32_t kd0,kd1,kn0,kn1;
  tf_host(0u,42u,0u,0u,kd0,kd1);   // k_dir
  tf_host(0u,42u,0u,1u,kn0,kn1);   // k_neg

  (void)hipMemsetAsync(praw, 0, 259*sizeof(float), stream);   // praw + acc

  k_pre     <<<248, 256, 0, stream>>>(q_feat, k_feat, q_bg, sal_q, sal_k, queue,
                                      q_flat, qbf, qnT, praw, tmp, llbl, acc);
  k_pnormfin<<<1,   256, 0, stream>>>(praw, pn, acc, sal);
  k_main    <<<N_MAIN4, 256, 0, stream>>>(q_flat, qbf, qnT, pn, logits, llog,
                                          kd0, kd1, kn0, kn1);
}